// Round 4
// baseline (167.899 us; speedup 1.0000x reference)
//
#include <hip/hip_runtime.h>

typedef unsigned short u16;
typedef __bf16 bf16x8 __attribute__((ext_vector_type(8)));
typedef float  f32x16 __attribute__((ext_vector_type(16)));

__device__ __forceinline__ u16 f2bf(float f) {
    union { float f; unsigned u; } v; v.f = f;
    return (u16)((v.u + 0x7fffu + ((v.u >> 16) & 1u)) >> 16);
}

#define GLD16(gsrc, ldst) \
    __builtin_amdgcn_global_load_lds( \
        (const __attribute__((address_space(1))) void*)(gsrc), \
        (__attribute__((address_space(3))) void*)(ldst), 16, 0, 0)

// ---------------------------------------------------------------------------
// 1) s_raw[b][c] = w[b] @ mod_w[c] + mod_b[c]
// ---------------------------------------------------------------------------
__global__ __launch_bounds__(256) void lin_kernel(
    const float* __restrict__ w, const float* __restrict__ mod_w,
    const float* __restrict__ mod_b, float* __restrict__ s_raw)
{
    int gw = (blockIdx.x * 256 + threadIdx.x) >> 6;
    int lane = threadIdx.x & 63;
    int b = gw >> 9, c = gw & 511;
    const float* wr = w + b * 512;
    const float* mr = mod_w + (size_t)c * 512;
    float a = 0.f;
#pragma unroll
    for (int i = 0; i < 8; ++i)
        a = fmaf(wr[lane + i * 64], mr[lane + i * 64], a);
    for (int off = 32; off; off >>= 1) a += __shfl_down(a, off);
    if (!lane) s_raw[gw] = a + mod_b[c];
}

// ---------------------------------------------------------------------------
// 2) s_eff = LeakyReLU(LN(s_raw)) * scale
// ---------------------------------------------------------------------------
__global__ __launch_bounds__(512) void norm_kernel(
    const float* __restrict__ s_raw, const float* __restrict__ ln_g,
    const float* __restrict__ ln_b, const float* __restrict__ scale,
    float* __restrict__ s_eff)
{
    int b = blockIdx.x, c = threadIdx.x;
    __shared__ float rs[512], rq[512];
    float s = s_raw[b * 512 + c];
    rs[c] = s; rq[c] = s * s;
    __syncthreads();
    for (int off = 256; off; off >>= 1) {
        if (c < off) { rs[c] += rs[c + off]; rq[c] += rq[c + off]; }
        __syncthreads();
    }
    float mean = rs[0] * (1.f / 512.f);
    float var  = rq[0] * (1.f / 512.f) - mean * mean;
    float sn = (s - mean) * rsqrtf(var + 1e-5f) * ln_g[c] + ln_b[c];
    sn = sn >= 0.f ? sn : 0.2f * sn;
    s_eff[b * 512 + c] = sn * scale[c];
}

// ---------------------------------------------------------------------------
// 3) wsq[co][ci] = sum_p weight^2 ; wbfT[(p*64+cg)*512*8 + co*8 + cj] = bf16(w)
// ---------------------------------------------------------------------------
__global__ __launch_bounds__(256) void wsq_kernel(
    const float* __restrict__ weight, float* __restrict__ wsq, u16* __restrict__ wbfT)
{
    int idx = blockIdx.x * 256 + threadIdx.x;      // co*512+ci
    int co = idx >> 9, ci = idx & 511;
    int cg = ci >> 3, cj = ci & 7;
    const float* wp = weight + (size_t)idx * 9;
    float s = 0.f;
#pragma unroll
    for (int p = 0; p < 9; ++p) {
        float v = wp[p];
        s += v * v;
        wbfT[((size_t)(p * 64 + cg) * 512 + co) * 8 + cj] = f2bf(v);
    }
    wsq[idx] = s;
}

// ---------------------------------------------------------------------------
// 4) xs[b][h][w][c] (NHWC bf16) = bf16(x[b][c][h][w] * s_eff[b][c])
// ---------------------------------------------------------------------------
__global__ __launch_bounds__(256) void xs_kernel(
    const float* __restrict__ x, const float* __restrict__ s_eff,
    u16* __restrict__ xs)
{
    const int bh = blockIdx.x;
    const int b = bh >> 5, h = bh & 31;
    __shared__ float tile[64][33];
    for (int c0 = 0; c0 < 512; c0 += 64) {
        if (c0) __syncthreads();
        for (int idx = threadIdx.x; idx < 2048; idx += 256) {
            int c = idx >> 5, ww = idx & 31;
            tile[c][ww] = x[(((size_t)b * 512 + c0 + c) * 32 + h) * 32 + ww]
                          * s_eff[b * 512 + c0 + c];
        }
        __syncthreads();
        for (int idx = threadIdx.x; idx < 2048; idx += 256) {
            int ww = idx >> 6, c = idx & 63;
            xs[((b * 32 + h) * 32 + ww) * 512 + c0 + c] = f2bf(tile[c][ww]);
        }
    }
}

// ---------------------------------------------------------------------------
// 5) dsc[b][o] = rsqrt(sum_i s_eff[b][i]^2 * wsq[o][i] + 1e-8)
// ---------------------------------------------------------------------------
__global__ __launch_bounds__(256) void dsc_kernel(
    const float* __restrict__ s_eff, const float* __restrict__ wsq,
    float* __restrict__ dsc)
{
    int gw = (blockIdx.x * 256 + threadIdx.x) >> 6;
    int lane = threadIdx.x & 63;
    int b = gw >> 9, co = gw & 511;
    float a = 0.f;
#pragma unroll
    for (int i = 0; i < 8; ++i) {
        int cin = lane + i * 64;
        float se = s_eff[b * 512 + cin];
        a += se * se * wsq[co * 512 + cin];
    }
    for (int off = 32; off; off >>= 1) a += __shfl_down(a, off);
    if (!lane) dsc[gw] = rsqrtf(a + 1e-8f);
}

// ---------------------------------------------------------------------------
// 6) zero page for halo OOB lanes
// ---------------------------------------------------------------------------
__global__ void zfill_kernel(float* p) { p[threadIdx.x] = 0.f; }

// ---------------------------------------------------------------------------
// 7) conv GEMM M=512 N=16384 K=4608.  512 blocks (mt=bx&3 XCD-pinned), 256 thr
//    = 4 waves (2M x 2N), wave tile 64x64.  A (weights) -> register prefetch
//    straight from L1/L2 (block-uniform stream per XCD).  B (x, im2col) -> LDS
//    via global_load_lds, double-buffered, conflict-free swizzle
//    kc = slot ^ ((px>>1)&3).  One barrier per 32-cin step.
// ---------------------------------------------------------------------------
__global__ __launch_bounds__(256) void conv_kernel(
    const u16* __restrict__ wbfT,  // [576 kflat8][512 co][8]
    const u16* __restrict__ xs,    // [16][32][32][512]
    const float* __restrict__ dsc, // [16][512]
    const u16* __restrict__ zp,    // >=16B zeros
    float* __restrict__ out)       // [16][512][32][32]
{
    __shared__ __align__(16) u16 lds[2][4096];   // B only: 8 KB per buf

    const int tid  = threadIdx.x;
    const int lane = tid & 63;
    const int wv   = tid >> 6;
    const int wm   = wv >> 1;        // cout half
    const int wn   = wv & 1;         // px half
    const int l31  = lane & 31;
    const int kc8  = lane >> 5;

    const int bx = blockIdx.x;
    const int mt = bx & 3;           // XCD-pinned cout tile
    const int nt = bx >> 2;
    const int b  = nt >> 3;
    const int h0 = (nt & 7) << 2;

    const u16* xsb = xs + (size_t)b * (32 * 32 * 512);

    // ---- B staging: 512 chunks/step; thread -> ch = tid, tid+256.
    // chunk ch: px = ch>>2, slot = ch&3 holds kc = slot ^ ((px>>1)&3).
    const int px0 = tid >> 2,            px1 = (tid + 256) >> 2;
    const int kcA = (tid & 3) ^ ((tid >> 3) & 3);
    const int kcB = ((tid + 256) & 3) ^ (((tid + 256) >> 3) & 3);
    const u16 *bb0, *bb1; bool bv0, bv1;
    auto setB = [&](int pos) {
        int kh = pos / 3 - 1, kw = pos % 3 - 1;
        int hh0 = h0 + (px0 >> 5) + kh, ww0 = (px0 & 31) + kw;
        int hh1 = h0 + (px1 >> 5) + kh, ww1 = (px1 & 31) + kw;
        bv0 = ((unsigned)hh0 < 32u) & ((unsigned)ww0 < 32u);
        bv1 = ((unsigned)hh1 < 32u) & ((unsigned)ww1 < 32u);
        bb0 = xsb + (hh0 * 32 + ww0) * 512 + kcA * 8;
        bb1 = xsb + (hh1 * 32 + ww1) * 512 + kcB * 8;
    };

    char* ldsb = (char*)lds;
    char* wdst = ldsb + wv * 1024;   // wave-uniform; HW adds lane*16
    auto stageB = [&](int buf, int c0) {
        char* d = wdst + buf * 8192;
        GLD16(bv0 ? bb0 + c0 : zp, d);
        GLD16(bv1 ? bb1 + c0 : zp, d + 4096);
    };

    // ---- A register prefetch: lane l -> co = mt*128+wm*64+mf*32+(l&31),
    // kcg = kk*2 + (l>>5); advance +16384 u16 per step.
    const u16* ap[2][2];
#pragma unroll
    for (int mf = 0; mf < 2; ++mf)
#pragma unroll
        for (int kk = 0; kk < 2; ++kk)
            ap[mf][kk] = wbfT + ((size_t)(kk * 2 + kc8) * 512
                                 + mt * 128 + wm * 64 + mf * 32 + l31) * 8;

    uint4 a_even[2][2], a_odd[2][2];
    auto loadA = [&](uint4 (&dst)[2][2]) {
#pragma unroll
        for (int mf = 0; mf < 2; ++mf)
#pragma unroll
            for (int kk = 0; kk < 2; ++kk) {
                dst[mf][kk] = *reinterpret_cast<const uint4*>(ap[mf][kk]);
                ap[mf][kk] += 16384;
            }
    };

    f32x16 acc[2][2] = {};
    auto compute = [&](int buf, uint4 (&af)[2][2]) {
        const char* base = ldsb + buf * 8192;
#pragma unroll
        for (int kk = 0; kk < 2; ++kk) {
            const int sl = (((kk * 2 + kc8) ^ ((l31 >> 1) & 3)) << 4);
            bf16x8 b0 = *reinterpret_cast<const bf16x8*>(
                base + (wn * 64 + l31) * 64 + sl);
            bf16x8 b1 = *reinterpret_cast<const bf16x8*>(
                base + (wn * 64 + 32 + l31) * 64 + sl);
            bf16x8 a0 = *reinterpret_cast<const bf16x8*>(&af[0][kk]);
            bf16x8 a1 = *reinterpret_cast<const bf16x8*>(&af[1][kk]);
            acc[0][0] = __builtin_amdgcn_mfma_f32_32x32x16_bf16(a0, b0, acc[0][0], 0, 0, 0);
            acc[0][1] = __builtin_amdgcn_mfma_f32_32x32x16_bf16(a0, b1, acc[0][1], 0, 0, 0);
            acc[1][0] = __builtin_amdgcn_mfma_f32_32x32x16_bf16(a1, b0, acc[1][0], 0, 0, 0);
            acc[1][1] = __builtin_amdgcn_mfma_f32_32x32x16_bf16(a1, b1, acc[1][1], 0, 0, 0);
        }
    };

    setB(0);
    stageB(0, 0);
    loadA(a_even);
    __syncthreads();   // buf0 + a_even resident

    for (int sp = 0; sp < 72; ++sp) {
        // ---- even step s = 2*sp: uses buf0 / a_even ----
        {
            const int sn = 2 * sp + 1;           // always < 144
            if ((sn & 15) == 0) setB(sn >> 4);
            stageB(1, (sn & 15) * 32);
            loadA(a_odd);
            compute(0, a_even);
            __syncthreads();
        }
        // ---- odd step s = 2*sp+1: uses buf1 / a_odd ----
        {
            const int sn = 2 * sp + 2;
            if (sn < 144) {
                if ((sn & 15) == 0) setB(sn >> 4);
                stageB(0, (sn & 15) * 32);
                loadA(a_even);
            }
            compute(1, a_odd);
            __syncthreads();
        }
    }

    // ---- epilogue: C/D layout col=lane&31, row=(q&3)+8*(q>>2)+4*(lane>>5) ----
    const float* db = dsc + b * 512;
#pragma unroll
    for (int mf = 0; mf < 2; ++mf) {
#pragma unroll
        for (int nf = 0; nf < 2; ++nf) {
            const int n = nt * 128 + wn * 64 + nf * 32 + l31;
            const int h = (n >> 5) & 31, w = n & 31;
#pragma unroll
            for (int q = 0; q < 16; ++q) {
                int row = (q & 3) + 8 * (q >> 2) + 4 * kc8;
                int co  = mt * 128 + wm * 64 + mf * 32 + row;
                out[(((size_t)b * 512 + co) * 32 + h) * 32 + w]
                    = acc[mf][nf][q] * db[co];
            }
        }
    }
}

// ---------------------------------------------------------------------------
extern "C" void kernel_launch(void* const* d_in, const int* in_sizes, int n_in,
                              void* d_out, int out_size, void* d_ws, size_t ws_size,
                              hipStream_t stream) {
    const float* x      = (const float*)d_in[0];
    const float* w      = (const float*)d_in[1];
    const float* mod_w  = (const float*)d_in[2];
    const float* mod_b  = (const float*)d_in[3];
    const float* ln_g   = (const float*)d_in[4];
    const float* ln_b   = (const float*)d_in[5];
    const float* weight = (const float*)d_in[6];
    const float* scale  = (const float*)d_in[7];
    float* out = (float*)d_out;

    char* ws = (char*)d_ws;
    float* s_raw = (float*)(ws);                     // 32 KB, reused as dsc
    float* dsc   = (float*)(ws);
    float* s_eff = (float*)(ws + 32768);             // 32 KB; head reused as zeros page
    float* wsq   = (float*)(ws + 65536);             // 1 MB
    u16*   wbfT  = (u16*)(ws + 65536 + 1048576);     // 4.5 MB
    u16*   xs    = (u16*)(ws + 65536 + 1048576 + 4718592);  // 16.78 MB
    if (ws_size < 22609920u) return;

    lin_kernel <<<2048, 256, 0, stream>>>(w, mod_w, mod_b, s_raw);
    wsq_kernel <<<1024, 256, 0, stream>>>(weight, wsq, wbfT);
    norm_kernel<<<16, 512, 0, stream>>>(s_raw, ln_g, ln_b, scale, s_eff);
    xs_kernel  <<<512, 256, 0, stream>>>(x, s_eff, xs);
    dsc_kernel <<<2048, 256, 0, stream>>>(s_eff, wsq, dsc);
    zfill_kernel<<<1, 1024, 0, stream>>>(s_eff);     // zeros page (s_eff dead now)
    conv_kernel<<<512, 256, 0, stream>>>(wbfT, xs, dsc, (const u16*)s_eff, out);
}

// Round 5
// 136.995 us; speedup vs baseline: 1.2256x; 1.2256x over previous
//
#include <hip/hip_runtime.h>

typedef unsigned short u16;
typedef __bf16 bf16x8 __attribute__((ext_vector_type(8)));
typedef float  f32x16 __attribute__((ext_vector_type(16)));

__device__ __forceinline__ u16 f2bf(float f) {
    union { float f; unsigned u; } v; v.f = f;
    return (u16)((v.u + 0x7fffu + ((v.u >> 16) & 1u)) >> 16);
}

#define GLD16(gsrc, ldst) \
    __builtin_amdgcn_global_load_lds( \
        (const __attribute__((address_space(1))) void*)(gsrc), \
        (__attribute__((address_space(3))) void*)(ldst), 16, 0, 0)

// ---------------------------------------------------------------------------
// 1) s_raw[b][c] = w[b] @ mod_w[c] + mod_b[c]
// ---------------------------------------------------------------------------
__global__ __launch_bounds__(256) void lin_kernel(
    const float* __restrict__ w, const float* __restrict__ mod_w,
    const float* __restrict__ mod_b, float* __restrict__ s_raw)
{
    int gw = (blockIdx.x * 256 + threadIdx.x) >> 6;
    int lane = threadIdx.x & 63;
    int b = gw >> 9, c = gw & 511;
    const float* wr = w + b * 512;
    const float* mr = mod_w + (size_t)c * 512;
    float a = 0.f;
#pragma unroll
    for (int i = 0; i < 8; ++i)
        a = fmaf(wr[lane + i * 64], mr[lane + i * 64], a);
    for (int off = 32; off; off >>= 1) a += __shfl_down(a, off);
    if (!lane) s_raw[gw] = a + mod_b[c];
}

// ---------------------------------------------------------------------------
// 2) s_eff = LeakyReLU(LN(s_raw)) * scale
// ---------------------------------------------------------------------------
__global__ __launch_bounds__(512) void norm_kernel(
    const float* __restrict__ s_raw, const float* __restrict__ ln_g,
    const float* __restrict__ ln_b, const float* __restrict__ scale,
    float* __restrict__ s_eff)
{
    int b = blockIdx.x, c = threadIdx.x;
    __shared__ float rs[512], rq[512];
    float s = s_raw[b * 512 + c];
    rs[c] = s; rq[c] = s * s;
    __syncthreads();
    for (int off = 256; off; off >>= 1) {
        if (c < off) { rs[c] += rs[c + off]; rq[c] += rq[c + off]; }
        __syncthreads();
    }
    float mean = rs[0] * (1.f / 512.f);
    float var  = rq[0] * (1.f / 512.f) - mean * mean;
    float sn = (s - mean) * rsqrtf(var + 1e-5f) * ln_g[c] + ln_b[c];
    sn = sn >= 0.f ? sn : 0.2f * sn;
    s_eff[b * 512 + c] = sn * scale[c];
}

// ---------------------------------------------------------------------------
// 3) wsq[co][ci] = sum_p weight^2 ; wbfT[(p*64+cg)*512*8 + co*8 + cj] = bf16(w)
// ---------------------------------------------------------------------------
__global__ __launch_bounds__(256) void wsq_kernel(
    const float* __restrict__ weight, float* __restrict__ wsq, u16* __restrict__ wbfT)
{
    int idx = blockIdx.x * 256 + threadIdx.x;      // co*512+ci
    int co = idx >> 9, ci = idx & 511;
    int cg = ci >> 3, cj = ci & 7;
    const float* wp = weight + (size_t)idx * 9;
    float s = 0.f;
#pragma unroll
    for (int p = 0; p < 9; ++p) {
        float v = wp[p];
        s += v * v;
        wbfT[((size_t)(p * 64 + cg) * 512 + co) * 8 + cj] = f2bf(v);
    }
    wsq[idx] = s;
}

// ---------------------------------------------------------------------------
// 4) xs[b][h][w][c] (NHWC bf16) = bf16(x[b][c][h][w] * s_eff[b][c])
// ---------------------------------------------------------------------------
__global__ __launch_bounds__(256) void xs_kernel(
    const float* __restrict__ x, const float* __restrict__ s_eff,
    u16* __restrict__ xs)
{
    const int bh = blockIdx.x;
    const int b = bh >> 5, h = bh & 31;
    __shared__ float tile[64][33];
    for (int c0 = 0; c0 < 512; c0 += 64) {
        if (c0) __syncthreads();
        for (int idx = threadIdx.x; idx < 2048; idx += 256) {
            int c = idx >> 5, ww = idx & 31;
            tile[c][ww] = x[(((size_t)b * 512 + c0 + c) * 32 + h) * 32 + ww]
                          * s_eff[b * 512 + c0 + c];
        }
        __syncthreads();
        for (int idx = threadIdx.x; idx < 2048; idx += 256) {
            int ww = idx >> 6, c = idx & 63;
            xs[((b * 32 + h) * 32 + ww) * 512 + c0 + c] = f2bf(tile[c][ww]);
        }
    }
}

// ---------------------------------------------------------------------------
// 5) dsc[b][o] = rsqrt(sum_i s_eff[b][i]^2 * wsq[o][i] + 1e-8)
// ---------------------------------------------------------------------------
__global__ __launch_bounds__(256) void dsc_kernel(
    const float* __restrict__ s_eff, const float* __restrict__ wsq,
    float* __restrict__ dsc)
{
    int gw = (blockIdx.x * 256 + threadIdx.x) >> 6;
    int lane = threadIdx.x & 63;
    int b = gw >> 9, co = gw & 511;
    float a = 0.f;
#pragma unroll
    for (int i = 0; i < 8; ++i) {
        int cin = lane + i * 64;
        float se = s_eff[b * 512 + cin];
        a += se * se * wsq[co * 512 + cin];
    }
    for (int off = 32; off; off >>= 1) a += __shfl_down(a, off);
    if (!lane) dsc[gw] = rsqrtf(a + 1e-8f);
}

// ---------------------------------------------------------------------------
// 6) zero page for halo OOB lanes
// ---------------------------------------------------------------------------
__global__ void zfill_kernel(float* p) { p[threadIdx.x] = 0.f; }

// ---------------------------------------------------------------------------
// 7) conv, halo-restage structure: per 32-cin round, stage [6 rows][34 cols]
//    [32 cin] halo tile ONCE (13056 B, double-buffered), compute all 9 taps
//    from LDS.  Grid 256 = 2 mt (XCD-parity-pinned) x 128 strips (b, 4 rows).
//    Block 512 thr = 8 waves (4M x 2N), wave tile 64 co x 64 px, BM=256.
//    A (weights) register-streamed from L1/L2, ping-pong, pos-unrolled.
//    Swizzle: chunk(p,slot) holds kc = slot ^ ((p>>1)&3), both sides.
// ---------------------------------------------------------------------------
__global__ __launch_bounds__(512) void conv_kernel(
    const u16* __restrict__ wbfT,  // [576 kflat8][512 co][8]
    const u16* __restrict__ xs,    // [16][32][32][512]
    const float* __restrict__ dsc, // [16][512]
    const u16* __restrict__ zp,    // >=16B zeros
    float* __restrict__ out)       // [16][512][32][32]
{
    __shared__ __align__(16) u16 lds[2 * 816 * 8];   // 2 x 13056 B

    const int tid  = threadIdx.x;
    const int lane = tid & 63;
    const int wv   = tid >> 6;       // 0..7
    const int wm   = wv >> 1;        // 0..3  M-wave
    const int wn   = wv & 1;         // 0..1  N-wave
    const int l31  = lane & 31;
    const int kc8  = lane >> 5;

    const int bx = blockIdx.x;       // 256 blocks
    const int mt = bx & 1;           // cout half, pinned per XCD parity
    const int nt = bx >> 1;          // 0..127
    const int b  = nt >> 3;
    const int h0 = (nt & 7) << 2;

    const u16* xsb = xs + (size_t)b * (32 * 32 * 512);

    // ---- halo staging descriptors: 816 chunks = 204 p x 4 slots x 16B ----
    const u16* sb[4]; bool sval[4], inb[4];
#pragma unroll
    for (int k = 0; k < 4; ++k) {
        int ch = tid + k * 512;
        sval[k] = ch < 816;
        int p = ch >> 2, slot = ch & 3;
        int kc = slot ^ ((p >> 1) & 3);
        int rr = p / 34, cc = p % 34;
        int hh = h0 - 1 + rr, ww = cc - 1;
        inb[k] = sval[k] && ((unsigned)hh < 32u) && ((unsigned)ww < 32u);
        sb[k] = xsb + (hh * 32 + ww) * 512 + kc * 8;
    }
    char* ldsb = (char*)lds;
    char* wdst = ldsb + wv * 1024;   // wave-uniform; HW adds lane*16

    auto stage = [&](int buf, int c0) {
        char* d = wdst + buf * 13056;
#pragma unroll
        for (int k = 0; k < 2; ++k)          // ch = tid, tid+512 (<816 iff tid<304)
            if (sval[k]) GLD16(inb[k] ? sb[k] + c0 : zp, d + k * 8192);
    };

    // ---- A pointers: co = mt*256 + wm*64 + mf*32 + l31, kc-group kk*2+kc8 ----
    const u16* apb[2];
#pragma unroll
    for (int mf = 0; mf < 2; ++mf)
        apb[mf] = wbfT + ((size_t)kc8 * 512 + mt * 256 + wm * 64 + mf * 32 + l31) * 8;
    // addr(pos, c0g, kk) = apb[mf] + ((pos*64 + c0g + kk*2) * 512) * 8

    uint4 aA[2][2], aB[2][2];        // ping/pong [mf][kk]
    auto loadA = [&](uint4 (&dst)[2][2], int pos, int c0g) {
#pragma unroll
        for (int mf = 0; mf < 2; ++mf)
#pragma unroll
            for (int kk = 0; kk < 2; ++kk)
                dst[mf][kk] = *reinterpret_cast<const uint4*>(
                    apb[mf] + ((size_t)(pos * 64 + c0g) + kk * 2) * 4096);
    };

    f32x16 acc[2][2] = {};

    stage(0, 0);
    loadA(aA, 0, 0);
    __syncthreads();                 // buf0 resident

    for (int r = 0; r < 16; ++r) {
        const int c0g = r * 4;
        const char* base = ldsb + (r & 1) * 13056;
        if (r < 15) stage((r + 1) & 1, (r + 1) * 32);   // flies over 9-tap phase

#pragma unroll
        for (int pos = 0; pos < 9; ++pos) {
            const int kh = pos / 3, kw = pos % 3;
            // prefetch next A (ping-pong, static after unroll)
            if (pos < 8) {
                if ((pos & 1) == 0) loadA(aB, pos + 1, c0g);
                else                loadA(aA, pos + 1, c0g);
            } else if (r < 15) {
                loadA(aB, 0, c0g + 4);       // first pos of next round -> aB
            }
#pragma unroll
            for (int kk = 0; kk < 2; ++kk) {
                const int sk = kk * 2 + kc8;
                bf16x8 bv[2];
#pragma unroll
                for (int nf = 0; nf < 2; ++nf) {
                    const int p = (wn * 2 + nf + kh) * 34 + l31 + kw;
                    bv[nf] = *reinterpret_cast<const bf16x8*>(
                        base + p * 64 + ((sk ^ ((p >> 1) & 3)) << 4));
                }
                const uint4* af = ((pos & 1) == 0) ? &aA[0][0] : &aB[0][0];
#pragma unroll
                for (int mf = 0; mf < 2; ++mf) {
                    bf16x8 av = *reinterpret_cast<const bf16x8*>(&af[mf * 2 + kk]);
                    acc[mf][0] = __builtin_amdgcn_mfma_f32_32x32x16_bf16(
                        av, bv[0], acc[mf][0], 0, 0, 0);
                    acc[mf][1] = __builtin_amdgcn_mfma_f32_32x32x16_bf16(
                        av, bv[1], acc[mf][1], 0, 0, 0);
                }
            }
        }
        // after pos 8 (odd): aB holds next round's pos-0 A; swap into aA
        if (r < 15) {
#pragma unroll
            for (int mf = 0; mf < 2; ++mf)
#pragma unroll
                for (int kk = 0; kk < 2; ++kk) aA[mf][kk] = aB[mf][kk];
        }
        __syncthreads();             // staged loads drained + buf swap safe
    }

    // ---- epilogue: C/D col=lane&31, row=(q&3)+8*(q>>2)+4*(lane>>5) ----
    const float* db = dsc + b * 512;
#pragma unroll
    for (int mf = 0; mf < 2; ++mf) {
#pragma unroll
        for (int nf = 0; nf < 2; ++nf) {
            const int px = wn * 64 + nf * 32 + l31;
            const int h = h0 + (px >> 5), w = px & 31;
#pragma unroll
            for (int q = 0; q < 16; ++q) {
                int row = (q & 3) + 8 * (q >> 2) + 4 * kc8;
                int co  = mt * 256 + wm * 64 + mf * 32 + row;
                out[(((size_t)b * 512 + co) * 32 + h) * 32 + w]
                    = acc[mf][nf][q] * db[co];
            }
        }
    }
}

// ---------------------------------------------------------------------------
extern "C" void kernel_launch(void* const* d_in, const int* in_sizes, int n_in,
                              void* d_out, int out_size, void* d_ws, size_t ws_size,
                              hipStream_t stream) {
    const float* x      = (const float*)d_in[0];
    const float* w      = (const float*)d_in[1];
    const float* mod_w  = (const float*)d_in[2];
    const float* mod_b  = (const float*)d_in[3];
    const float* ln_g   = (const float*)d_in[4];
    const float* ln_b   = (const float*)d_in[5];
    const float* weight = (const float*)d_in[6];
    const float* scale  = (const float*)d_in[7];
    float* out = (float*)d_out;

    char* ws = (char*)d_ws;
    float* s_raw = (float*)(ws);                     // 32 KB, reused as dsc
    float* dsc   = (float*)(ws);
    float* s_eff = (float*)(ws + 32768);             // 32 KB; head reused as zeros page
    float* wsq   = (float*)(ws + 65536);             // 1 MB
    u16*   wbfT  = (u16*)(ws + 65536 + 1048576);     // 4.5 MB
    u16*   xs    = (u16*)(ws + 65536 + 1048576 + 4718592);  // 16.78 MB
    if (ws_size < 22609920u) return;

    lin_kernel <<<2048, 256, 0, stream>>>(w, mod_w, mod_b, s_raw);
    wsq_kernel <<<1024, 256, 0, stream>>>(weight, wsq, wbfT);
    norm_kernel<<<16, 512, 0, stream>>>(s_raw, ln_g, ln_b, scale, s_eff);
    xs_kernel  <<<512, 256, 0, stream>>>(x, s_eff, xs);
    dsc_kernel <<<2048, 256, 0, stream>>>(s_eff, wsq, dsc);
    zfill_kernel<<<1, 1024, 0, stream>>>(s_eff);     // zeros page (s_eff dead now)
    conv_kernel<<<256, 512, 0, stream>>>(wbfT, xs, dsc, (const u16*)s_eff, out);
}

// Round 6
// 136.354 us; speedup vs baseline: 1.2313x; 1.0047x over previous
//
#include <hip/hip_runtime.h>

typedef unsigned short u16;
typedef __bf16 bf16x8 __attribute__((ext_vector_type(8)));
typedef float  f32x16 __attribute__((ext_vector_type(16)));

__device__ __forceinline__ u16 f2bf(float f) {
    union { float f; unsigned u; } v; v.f = f;
    return (u16)((v.u + 0x7fffu + ((v.u >> 16) & 1u)) >> 16);
}

#define GLD16(gsrc, ldst) \
    __builtin_amdgcn_global_load_lds( \
        (const __attribute__((address_space(1))) void*)(gsrc), \
        (__attribute__((address_space(3))) void*)(ldst), 16, 0, 0)

// ---------------------------------------------------------------------------
// 1) s_raw[b][c] = w[b] @ mod_w[c] + mod_b[c]
// ---------------------------------------------------------------------------
__global__ __launch_bounds__(256) void lin_kernel(
    const float* __restrict__ w, const float* __restrict__ mod_w,
    const float* __restrict__ mod_b, float* __restrict__ s_raw)
{
    int gw = (blockIdx.x * 256 + threadIdx.x) >> 6;
    int lane = threadIdx.x & 63;
    int b = gw >> 9, c = gw & 511;
    const float* wr = w + b * 512;
    const float* mr = mod_w + (size_t)c * 512;
    float a = 0.f;
#pragma unroll
    for (int i = 0; i < 8; ++i)
        a = fmaf(wr[lane + i * 64], mr[lane + i * 64], a);
    for (int off = 32; off; off >>= 1) a += __shfl_down(a, off);
    if (!lane) s_raw[gw] = a + mod_b[c];
}

// ---------------------------------------------------------------------------
// 2) s_eff = LeakyReLU(LN(s_raw)) * scale
// ---------------------------------------------------------------------------
__global__ __launch_bounds__(512) void norm_kernel(
    const float* __restrict__ s_raw, const float* __restrict__ ln_g,
    const float* __restrict__ ln_b, const float* __restrict__ scale,
    float* __restrict__ s_eff)
{
    int b = blockIdx.x, c = threadIdx.x;
    __shared__ float rs[512], rq[512];
    float s = s_raw[b * 512 + c];
    rs[c] = s; rq[c] = s * s;
    __syncthreads();
    for (int off = 256; off; off >>= 1) {
        if (c < off) { rs[c] += rs[c + off]; rq[c] += rq[c + off]; }
        __syncthreads();
    }
    float mean = rs[0] * (1.f / 512.f);
    float var  = rq[0] * (1.f / 512.f) - mean * mean;
    float sn = (s - mean) * rsqrtf(var + 1e-5f) * ln_g[c] + ln_b[c];
    sn = sn >= 0.f ? sn : 0.2f * sn;
    s_eff[b * 512 + c] = sn * scale[c];
}

// ---------------------------------------------------------------------------
// 3) wsq[co][ci] = sum_p weight^2 ; wbfT[(p*64+cg)*512*8 + co*8 + cj] = bf16(w)
// ---------------------------------------------------------------------------
__global__ __launch_bounds__(256) void wsq_kernel(
    const float* __restrict__ weight, float* __restrict__ wsq, u16* __restrict__ wbfT)
{
    int idx = blockIdx.x * 256 + threadIdx.x;      // co*512+ci
    int co = idx >> 9, ci = idx & 511;
    int cg = ci >> 3, cj = ci & 7;
    const float* wp = weight + (size_t)idx * 9;
    float s = 0.f;
#pragma unroll
    for (int p = 0; p < 9; ++p) {
        float v = wp[p];
        s += v * v;
        wbfT[((size_t)(p * 64 + cg) * 512 + co) * 8 + cj] = f2bf(v);
    }
    wsq[idx] = s;
}

// ---------------------------------------------------------------------------
// 4) xs[b][h][w][c] (NHWC bf16) = bf16(x[b][c][h][w] * s_eff[b][c])
// ---------------------------------------------------------------------------
__global__ __launch_bounds__(256) void xs_kernel(
    const float* __restrict__ x, const float* __restrict__ s_eff,
    u16* __restrict__ xs)
{
    const int bh = blockIdx.x;
    const int b = bh >> 5, h = bh & 31;
    __shared__ float tile[64][33];
    for (int c0 = 0; c0 < 512; c0 += 64) {
        if (c0) __syncthreads();
        for (int idx = threadIdx.x; idx < 2048; idx += 256) {
            int c = idx >> 5, ww = idx & 31;
            tile[c][ww] = x[(((size_t)b * 512 + c0 + c) * 32 + h) * 32 + ww]
                          * s_eff[b * 512 + c0 + c];
        }
        __syncthreads();
        for (int idx = threadIdx.x; idx < 2048; idx += 256) {
            int ww = idx >> 6, c = idx & 63;
            xs[((b * 32 + h) * 32 + ww) * 512 + c0 + c] = f2bf(tile[c][ww]);
        }
    }
}

// ---------------------------------------------------------------------------
// 5) dsc[b][o] = rsqrt(sum_i s_eff[b][i]^2 * wsq[o][i] + 1e-8)
// ---------------------------------------------------------------------------
__global__ __launch_bounds__(256) void dsc_kernel(
    const float* __restrict__ s_eff, const float* __restrict__ wsq,
    float* __restrict__ dsc)
{
    int gw = (blockIdx.x * 256 + threadIdx.x) >> 6;
    int lane = threadIdx.x & 63;
    int b = gw >> 9, co = gw & 511;
    float a = 0.f;
#pragma unroll
    for (int i = 0; i < 8; ++i) {
        int cin = lane + i * 64;
        float se = s_eff[b * 512 + cin];
        a += se * se * wsq[co * 512 + cin];
    }
    for (int off = 32; off; off >>= 1) a += __shfl_down(a, off);
    if (!lane) dsc[gw] = rsqrtf(a + 1e-8f);
}

// ---------------------------------------------------------------------------
// 6) zero page for halo OOB lanes
// ---------------------------------------------------------------------------
__global__ void zfill_kernel(float* p) { p[threadIdx.x] = 0.f; }

// ---------------------------------------------------------------------------
// 7) conv, halo-restage, 2 blocks/CU for barrier overlap.
//    Grid 512 = 2 mt (XCD-parity-pinned) x 256 strips (b, 2 rows).
//    Block 256 thr = 4 waves (4M x 1N), wave 64 co x 64 px, BM=256, BN=64.
//    Per 32-cin round: stage halo [4][34][32] ONCE (8704 B, double-buffered),
//    9 taps from LDS.  A register-streamed from L1/L2 (identical stream for
//    co-resident blocks -> L1-shared), ping-pong, pos-unrolled.
//    Swizzle: chunk(p,slot) holds kc = slot ^ ((p>>1)&3), both sides.
// ---------------------------------------------------------------------------
__global__ __launch_bounds__(256, 2) void conv_kernel(
    const u16* __restrict__ wbfT,  // [576 kflat8][512 co][8]
    const u16* __restrict__ xs,    // [16][32][32][512]
    const float* __restrict__ dsc, // [16][512]
    const u16* __restrict__ zp,    // >=16B zeros
    float* __restrict__ out)       // [16][512][32][32]
{
    __shared__ __align__(16) u16 lds[2 * 544 * 8];   // 2 x 8704 B

    const int tid  = threadIdx.x;
    const int lane = tid & 63;
    const int wv   = tid >> 6;       // 0..3  M-wave
    const int l31  = lane & 31;
    const int kc8  = lane >> 5;

    const int bx = blockIdx.x;       // 512 blocks
    const int mt = bx & 1;           // cout half, pinned per XCD parity
    const int nt = bx >> 1;          // 0..255
    const int b  = nt >> 4;
    const int h0 = (nt & 15) << 1;   // output rows h0, h0+1

    const u16* xsb = xs + (size_t)b * (32 * 32 * 512);

    // ---- halo staging descriptors: 544 chunks = 136 p x 4 slots x 16B ----
    const u16* sb[3]; bool sval[3], inb[3];
#pragma unroll
    for (int k = 0; k < 3; ++k) {
        int ch = tid + k * 256;
        sval[k] = ch < 544;
        int p = ch >> 2, slot = ch & 3;
        int kc = slot ^ ((p >> 1) & 3);
        int rr = p / 34, cc = p % 34;
        int hh = h0 - 1 + rr, ww = cc - 1;
        inb[k] = sval[k] && ((unsigned)hh < 32u) && ((unsigned)ww < 32u);
        sb[k] = xsb + (hh * 32 + ww) * 512 + kc * 8;
    }
    char* ldsb = (char*)lds;
    char* wdst = ldsb + wv * 1024;   // wave-uniform; HW adds lane*16

    auto stage = [&](int buf, int c0) {
        char* d = wdst + buf * 8704;
        GLD16(inb[0] ? sb[0] + c0 : zp, d);
        GLD16(inb[1] ? sb[1] + c0 : zp, d + 4096);
        if (sval[2]) GLD16(inb[2] ? sb[2] + c0 : zp, d + 8192);
    };

    // ---- A pointers: co = mt*256 + wv*64 + mf*32 + l31, kc-group kk*2+kc8 ----
    const u16* apb[2];
#pragma unroll
    for (int mf = 0; mf < 2; ++mf)
        apb[mf] = wbfT + ((size_t)kc8 * 512 + mt * 256 + wv * 64 + mf * 32 + l31) * 8;

    uint4 aA[2][2], aB[2][2];        // ping/pong [mf][kk]
    auto loadA = [&](uint4 (&dst)[2][2], int pos, int c0g) {
#pragma unroll
        for (int mf = 0; mf < 2; ++mf)
#pragma unroll
            for (int kk = 0; kk < 2; ++kk)
                dst[mf][kk] = *reinterpret_cast<const uint4*>(
                    apb[mf] + ((size_t)(pos * 64 + c0g) + kk * 2) * 4096);
    };

    f32x16 acc[2][2] = {};

    stage(0, 0);
    loadA(aA, 0, 0);
    __syncthreads();                 // buf0 resident

    for (int r = 0; r < 16; ++r) {
        const int c0g = r * 4;
        const char* base = ldsb + (r & 1) * 8704;
        if (r < 15) stage((r + 1) & 1, (r + 1) * 32);   // flies over 9-tap phase

#pragma unroll
        for (int pos = 0; pos < 9; ++pos) {
            const int kh = pos / 3, kw = pos % 3;
            if (pos < 8) {
                if ((pos & 1) == 0) loadA(aB, pos + 1, c0g);
                else                loadA(aA, pos + 1, c0g);
            } else if (r < 15) {
                loadA(aB, 0, c0g + 4);       // first pos of next round -> aB
            }
#pragma unroll
            for (int kk = 0; kk < 2; ++kk) {
                const int sk = kk * 2 + kc8;
                bf16x8 bv[2];
#pragma unroll
                for (int nf = 0; nf < 2; ++nf) {
                    const int p = (nf + kh) * 34 + l31 + kw;
                    bv[nf] = *reinterpret_cast<const bf16x8*>(
                        base + p * 64 + ((sk ^ ((p >> 1) & 3)) << 4));
                }
                const uint4* af = ((pos & 1) == 0) ? &aA[0][0] : &aB[0][0];
#pragma unroll
                for (int mf = 0; mf < 2; ++mf) {
                    bf16x8 av = *reinterpret_cast<const bf16x8*>(&af[mf * 2 + kk]);
                    acc[mf][0] = __builtin_amdgcn_mfma_f32_32x32x16_bf16(
                        av, bv[0], acc[mf][0], 0, 0, 0);
                    acc[mf][1] = __builtin_amdgcn_mfma_f32_32x32x16_bf16(
                        av, bv[1], acc[mf][1], 0, 0, 0);
                }
            }
        }
        if (r < 15) {
#pragma unroll
            for (int mf = 0; mf < 2; ++mf)
#pragma unroll
                for (int kk = 0; kk < 2; ++kk) aA[mf][kk] = aB[mf][kk];
        }
        __syncthreads();             // staged loads drained + buf swap safe
    }

    // ---- epilogue: C/D col=lane&31, row=(q&3)+8*(q>>2)+4*(lane>>5) ----
    const float* db = dsc + b * 512;
#pragma unroll
    for (int mf = 0; mf < 2; ++mf) {
#pragma unroll
        for (int nf = 0; nf < 2; ++nf) {
            const int h = h0 + nf, w = l31;
#pragma unroll
            for (int q = 0; q < 16; ++q) {
                int row = (q & 3) + 8 * (q >> 2) + 4 * kc8;
                int co  = mt * 256 + wv * 64 + mf * 32 + row;
                out[(((size_t)b * 512 + co) * 32 + h) * 32 + w]
                    = acc[mf][nf][q] * db[co];
            }
        }
    }
}

// ---------------------------------------------------------------------------
extern "C" void kernel_launch(void* const* d_in, const int* in_sizes, int n_in,
                              void* d_out, int out_size, void* d_ws, size_t ws_size,
                              hipStream_t stream) {
    const float* x      = (const float*)d_in[0];
    const float* w      = (const float*)d_in[1];
    const float* mod_w  = (const float*)d_in[2];
    const float* mod_b  = (const float*)d_in[3];
    const float* ln_g   = (const float*)d_in[4];
    const float* ln_b   = (const float*)d_in[5];
    const float* weight = (const float*)d_in[6];
    const float* scale  = (const float*)d_in[7];
    float* out = (float*)d_out;

    char* ws = (char*)d_ws;
    float* s_raw = (float*)(ws);                     // 32 KB, reused as dsc
    float* dsc   = (float*)(ws);
    float* s_eff = (float*)(ws + 32768);             // 32 KB; head reused as zeros page
    float* wsq   = (float*)(ws + 65536);             // 1 MB
    u16*   wbfT  = (u16*)(ws + 65536 + 1048576);     // 4.5 MB
    u16*   xs    = (u16*)(ws + 65536 + 1048576 + 4718592);  // 16.78 MB
    if (ws_size < 22609920u) return;

    lin_kernel <<<2048, 256, 0, stream>>>(w, mod_w, mod_b, s_raw);
    wsq_kernel <<<1024, 256, 0, stream>>>(weight, wsq, wbfT);
    norm_kernel<<<16, 512, 0, stream>>>(s_raw, ln_g, ln_b, scale, s_eff);
    xs_kernel  <<<512, 256, 0, stream>>>(x, s_eff, xs);
    dsc_kernel <<<2048, 256, 0, stream>>>(s_eff, wsq, dsc);
    zfill_kernel<<<1, 1024, 0, stream>>>(s_eff);     // zeros page (s_eff dead now)
    conv_kernel<<<512, 256, 0, stream>>>(wbfT, xs, dsc, (const u16*)s_eff, out);
}

// Round 7
// 135.701 us; speedup vs baseline: 1.2373x; 1.0048x over previous
//
#include <hip/hip_runtime.h>

typedef unsigned short u16;
typedef __bf16 bf16x8 __attribute__((ext_vector_type(8)));
typedef float  f32x16 __attribute__((ext_vector_type(16)));

__device__ __forceinline__ u16 f2bf(float f) {
    union { float f; unsigned u; } v; v.f = f;
    return (u16)((v.u + 0x7fffu + ((v.u >> 16) & 1u)) >> 16);
}

#define GLD16(gsrc, ldst) \
    __builtin_amdgcn_global_load_lds( \
        (const __attribute__((address_space(1))) void*)(gsrc), \
        (__attribute__((address_space(3))) void*)(ldst), 16, 0, 0)

// ---------------------------------------------------------------------------
// 1) s_raw[b][c] = w[b] @ mod_w[c] + mod_b[c]
// ---------------------------------------------------------------------------
__global__ __launch_bounds__(256) void lin_kernel(
    const float* __restrict__ w, const float* __restrict__ mod_w,
    const float* __restrict__ mod_b, float* __restrict__ s_raw)
{
    int gw = (blockIdx.x * 256 + threadIdx.x) >> 6;
    int lane = threadIdx.x & 63;
    int b = gw >> 9, c = gw & 511;
    const float* wr = w + b * 512;
    const float* mr = mod_w + (size_t)c * 512;
    float a = 0.f;
#pragma unroll
    for (int i = 0; i < 8; ++i)
        a = fmaf(wr[lane + i * 64], mr[lane + i * 64], a);
    for (int off = 32; off; off >>= 1) a += __shfl_down(a, off);
    if (!lane) s_raw[gw] = a + mod_b[c];
}

// ---------------------------------------------------------------------------
// 2) s_eff = LeakyReLU(LN(s_raw)) * scale
// ---------------------------------------------------------------------------
__global__ __launch_bounds__(512) void norm_kernel(
    const float* __restrict__ s_raw, const float* __restrict__ ln_g,
    const float* __restrict__ ln_b, const float* __restrict__ scale,
    float* __restrict__ s_eff)
{
    int b = blockIdx.x, c = threadIdx.x;
    __shared__ float rs[512], rq[512];
    float s = s_raw[b * 512 + c];
    rs[c] = s; rq[c] = s * s;
    __syncthreads();
    for (int off = 256; off; off >>= 1) {
        if (c < off) { rs[c] += rs[c + off]; rq[c] += rq[c + off]; }
        __syncthreads();
    }
    float mean = rs[0] * (1.f / 512.f);
    float var  = rq[0] * (1.f / 512.f) - mean * mean;
    float sn = (s - mean) * rsqrtf(var + 1e-5f) * ln_g[c] + ln_b[c];
    sn = sn >= 0.f ? sn : 0.2f * sn;
    s_eff[b * 512 + c] = sn * scale[c];
}

// ---------------------------------------------------------------------------
// 3) wsq[co][ci] = sum_p weight^2 ; wbfT[(p*64+cg)*512*8 + co*8 + cj] = bf16(w)
// ---------------------------------------------------------------------------
__global__ __launch_bounds__(256) void wsq_kernel(
    const float* __restrict__ weight, float* __restrict__ wsq, u16* __restrict__ wbfT)
{
    int idx = blockIdx.x * 256 + threadIdx.x;      // co*512+ci
    int co = idx >> 9, ci = idx & 511;
    int cg = ci >> 3, cj = ci & 7;
    const float* wp = weight + (size_t)idx * 9;
    float s = 0.f;
#pragma unroll
    for (int p = 0; p < 9; ++p) {
        float v = wp[p];
        s += v * v;
        wbfT[((size_t)(p * 64 + cg) * 512 + co) * 8 + cj] = f2bf(v);
    }
    wsq[idx] = s;
}

// ---------------------------------------------------------------------------
// 4) xs[b][h][w][c] (NHWC bf16) = bf16(x[b][c][h][w] * s_eff[b][c])
// ---------------------------------------------------------------------------
__global__ __launch_bounds__(256) void xs_kernel(
    const float* __restrict__ x, const float* __restrict__ s_eff,
    u16* __restrict__ xs)
{
    const int bh = blockIdx.x;
    const int b = bh >> 5, h = bh & 31;
    __shared__ float tile[64][33];
    for (int c0 = 0; c0 < 512; c0 += 64) {
        if (c0) __syncthreads();
        for (int idx = threadIdx.x; idx < 2048; idx += 256) {
            int c = idx >> 5, ww = idx & 31;
            tile[c][ww] = x[(((size_t)b * 512 + c0 + c) * 32 + h) * 32 + ww]
                          * s_eff[b * 512 + c0 + c];
        }
        __syncthreads();
        for (int idx = threadIdx.x; idx < 2048; idx += 256) {
            int ww = idx >> 6, c = idx & 63;
            xs[((b * 32 + h) * 32 + ww) * 512 + c0 + c] = f2bf(tile[c][ww]);
        }
    }
}

// ---------------------------------------------------------------------------
// 5) dsc[b][o] = rsqrt(sum_i s_eff[b][i]^2 * wsq[o][i] + 1e-8)
// ---------------------------------------------------------------------------
__global__ __launch_bounds__(256) void dsc_kernel(
    const float* __restrict__ s_eff, const float* __restrict__ wsq,
    float* __restrict__ dsc)
{
    int gw = (blockIdx.x * 256 + threadIdx.x) >> 6;
    int lane = threadIdx.x & 63;
    int b = gw >> 9, co = gw & 511;
    float a = 0.f;
#pragma unroll
    for (int i = 0; i < 8; ++i) {
        int cin = lane + i * 64;
        float se = s_eff[b * 512 + cin];
        a += se * se * wsq[co * 512 + cin];
    }
    for (int off = 32; off; off >>= 1) a += __shfl_down(a, off);
    if (!lane) dsc[gw] = rsqrtf(a + 1e-8f);
}

// ---------------------------------------------------------------------------
// 6) zero page for halo OOB lanes
// ---------------------------------------------------------------------------
__global__ void zfill_kernel(float* p) { p[threadIdx.x] = 0.f; }

// ---------------------------------------------------------------------------
// 7) conv, halo-restage + full reg ping-pong pipeline.
//    Grid 512 = 2 mt (XCD-parity-pinned) x 256 strips (b, 2 rows).
//    Block 256 thr = 4 waves (4M x 1N), wave 64 co x 64 px, BM=256, BN=64.
//    Per 32-cin round: stage halo [4][34][32] once (8704 B, dbuf), 9 taps.
//    A (global) AND B (LDS) fragments prefetched ONE POS AHEAD into ping-pong
//    regs -> MFMA never waits on a just-issued ds_read. Counted-vmcnt barrier
//    (never drains to 0 mid-loop).
// ---------------------------------------------------------------------------
__global__ __launch_bounds__(256, 2) void conv_kernel(
    const u16* __restrict__ wbfT,  // [576 kflat8][512 co][8]
    const u16* __restrict__ xs,    // [16][32][32][512]
    const float* __restrict__ dsc, // [16][512]
    const u16* __restrict__ zp,    // >=16B zeros
    float* __restrict__ out)       // [16][512][32][32]
{
    __shared__ __align__(16) u16 lds[2 * 544 * 8];   // 2 x 8704 B

    const int tid  = threadIdx.x;
    const int lane = tid & 63;
    const int wv   = tid >> 6;       // 0..3  M-wave
    const int l31  = lane & 31;
    const int kc8  = lane >> 5;

    const int bx = blockIdx.x;       // 512 blocks
    const int mt = bx & 1;           // cout half, pinned per XCD parity
    const int nt = bx >> 1;          // 0..255
    const int b  = nt >> 4;
    const int h0 = (nt & 15) << 1;   // output rows h0, h0+1

    const u16* xsb = xs + (size_t)b * (32 * 32 * 512);

    // ---- halo staging descriptors: 544 chunks = 136 p x 4 slots x 16B ----
    const u16* sb[3]; bool sval[3], inb[3];
#pragma unroll
    for (int k = 0; k < 3; ++k) {
        int ch = tid + k * 256;
        sval[k] = ch < 544;
        int p = ch >> 2, slot = ch & 3;
        int kc = slot ^ ((p >> 1) & 3);
        int rr = p / 34, cc = p % 34;
        int hh = h0 - 1 + rr, ww = cc - 1;
        inb[k] = sval[k] && ((unsigned)hh < 32u) && ((unsigned)ww < 32u);
        sb[k] = xsb + (hh * 32 + ww) * 512 + kc * 8;
    }
    char* ldsb = (char*)lds;
    char* wdst = ldsb + wv * 1024;   // wave-uniform; HW adds lane*16

    auto stage = [&](int buf, int c0) {
        char* d = wdst + buf * 8704;
        GLD16(inb[0] ? sb[0] + c0 : zp, d);
        GLD16(inb[1] ? sb[1] + c0 : zp, d + 4096);
        if (sval[2]) GLD16(inb[2] ? sb[2] + c0 : zp, d + 8192);
    };

    // ---- A pointers: co = mt*256 + wv*64 + mf*32 + l31, kc-group kk*2+kc8 ----
    const u16* apb[2];
#pragma unroll
    for (int mf = 0; mf < 2; ++mf)
        apb[mf] = wbfT + ((size_t)kc8 * 512 + mt * 256 + wv * 64 + mf * 32 + l31) * 8;

    uint4 aA[2][2], aB[2][2];        // ping/pong [mf][kk]
    auto loadA = [&](uint4 (&dst)[2][2], int pos, int c0g) {
#pragma unroll
        for (int mf = 0; mf < 2; ++mf)
#pragma unroll
            for (int kk = 0; kk < 2; ++kk)
                dst[mf][kk] = *reinterpret_cast<const uint4*>(
                    apb[mf] + ((size_t)(pos * 64 + c0g) + kk * 2) * 4096);
    };

    // ---- B register ping-pong: [kk][nf] ----
    bf16x8 bvA[2][2], bvB[2][2];
    auto loadB = [&](bf16x8 (&dst)[2][2], const char* base, int pos) {
        const int kh = pos / 3, kw = pos % 3;
#pragma unroll
        for (int kk = 0; kk < 2; ++kk) {
            const int sk = kk * 2 + kc8;
#pragma unroll
            for (int nf = 0; nf < 2; ++nf) {
                const int p = (nf + kh) * 34 + l31 + kw;
                dst[kk][nf] = *reinterpret_cast<const bf16x8*>(
                    base + p * 64 + ((sk ^ ((p >> 1) & 3)) << 4));
            }
        }
    };

    f32x16 acc[2][2] = {};
    auto domfma = [&](uint4 (&af)[2][2], bf16x8 (&bf)[2][2]) {
#pragma unroll
        for (int kk = 0; kk < 2; ++kk)
#pragma unroll
            for (int mf = 0; mf < 2; ++mf) {
                bf16x8 av = *reinterpret_cast<const bf16x8*>(&af[mf][kk]);
                acc[mf][0] = __builtin_amdgcn_mfma_f32_32x32x16_bf16(
                    av, bf[kk][0], acc[mf][0], 0, 0, 0);
                acc[mf][1] = __builtin_amdgcn_mfma_f32_32x32x16_bf16(
                    av, bf[kk][1], acc[mf][1], 0, 0, 0);
            }
    };

    stage(0, 0);
    loadA(aA, 0, 0);
    __syncthreads();                 // one-time full drain: buf0 resident

    for (int r = 0; r < 16; ++r) {
        const int c0g = r * 4;
        const char* base = ldsb + (r & 1) * 8704;
        if (r < 15) stage((r + 1) & 1, (r + 1) * 32);   // flies over 9-tap phase
        loadB(bvA, base, 0);         // only exposed ds_read stall this round

#pragma unroll
        for (int pos = 0; pos < 9; ++pos) {
            if (pos < 8) {
                // prefetch pos+1 into the other regs (static by unroll parity)
                if ((pos & 1) == 0) { loadA(aB, pos + 1, c0g); loadB(bvB, base, pos + 1); }
                else                { loadA(aA, pos + 1, c0g); loadB(bvA, base, pos + 1); }
            } else if (r < 15) {
                loadA(aB, 0, c0g + 4);       // next round pos0 A
            }
            if ((pos & 1) == 0) domfma(aA, bvA);
            else                domfma(aB, bvB);
        }
        if (r < 15) {
#pragma unroll
            for (int mf = 0; mf < 2; ++mf)
#pragma unroll
                for (int kk = 0; kk < 2; ++kk) aA[mf][kk] = aB[mf][kk];
            // counted barrier: stage GLD16s are older than pos8's A-wait ->
            // already retired; allow the 4 fresh next-pos0 A-loads to fly.
            asm volatile("s_waitcnt vmcnt(4)" ::: "memory");
            __builtin_amdgcn_s_barrier();
            asm volatile("" ::: "memory");
        }
    }

    // ---- epilogue: C/D col=lane&31, row=(q&3)+8*(q>>2)+4*(lane>>5) ----
    const float* db = dsc + b * 512;
#pragma unroll
    for (int mf = 0; mf < 2; ++mf) {
#pragma unroll
        for (int nf = 0; nf < 2; ++nf) {
            const int h = h0 + nf, w = l31;
#pragma unroll
            for (int q = 0; q < 16; ++q) {
                int row = (q & 3) + 8 * (q >> 2) + 4 * kc8;
                int co  = mt * 256 + wv * 64 + mf * 32 + row;
                out[(((size_t)b * 512 + co) * 32 + h) * 32 + w]
                    = acc[mf][nf][q] * db[co];
            }
        }
    }
}

// ---------------------------------------------------------------------------
extern "C" void kernel_launch(void* const* d_in, const int* in_sizes, int n_in,
                              void* d_out, int out_size, void* d_ws, size_t ws_size,
                              hipStream_t stream) {
    const float* x      = (const float*)d_in[0];
    const float* w      = (const float*)d_in[1];
    const float* mod_w  = (const float*)d_in[2];
    const float* mod_b  = (const float*)d_in[3];
    const float* ln_g   = (const float*)d_in[4];
    const float* ln_b   = (const float*)d_in[5];
    const float* weight = (const float*)d_in[6];
    const float* scale  = (const float*)d_in[7];
    float* out = (float*)d_out;

    char* ws = (char*)d_ws;
    float* s_raw = (float*)(ws);                     // 32 KB, reused as dsc
    float* dsc   = (float*)(ws);
    float* s_eff = (float*)(ws + 32768);             // 32 KB; head reused as zeros page
    float* wsq   = (float*)(ws + 65536);             // 1 MB
    u16*   wbfT  = (u16*)(ws + 65536 + 1048576);     // 4.5 MB
    u16*   xs    = (u16*)(ws + 65536 + 1048576 + 4718592);  // 16.78 MB
    if (ws_size < 22609920u) return;

    lin_kernel <<<2048, 256, 0, stream>>>(w, mod_w, mod_b, s_raw);
    wsq_kernel <<<1024, 256, 0, stream>>>(weight, wsq, wbfT);
    norm_kernel<<<16, 512, 0, stream>>>(s_raw, ln_g, ln_b, scale, s_eff);
    xs_kernel  <<<512, 256, 0, stream>>>(x, s_eff, xs);
    dsc_kernel <<<2048, 256, 0, stream>>>(s_eff, wsq, dsc);
    zfill_kernel<<<1, 1024, 0, stream>>>(s_eff);     // zeros page (s_eff dead now)
    conv_kernel<<<512, 256, 0, stream>>>(wbfT, xs, dsc, (const u16*)s_eff, out);
}